// Round 1
// baseline (80.726 us; speedup 1.0000x reference)
//
#include <hip/hip_runtime.h>
#include <math.h>

#define NPTS 10000
#define TILE 1000          // y-points staged per LDS pass (float4 = 16 KB)
#define XCHUNKS 40         // ceil(10000/256)

// ---------------------------------------------------------------------------
// Kernel A: per (combo, slice, x-chunk) partial nearest-neighbor search.
// combo c in [0,4): dir = c>>1 (0: target->pred, 1: pred->target), b = c&1.
// Maximize m_j = dot(x, y_j) - 0.5*|y_j|^2  (equiv. minimize d2, since
// d2 = -2*(m + hx) with hx = -0.5*|x|^2 constant per thread).
// Strict > keeps the FIRST occurrence -> matches jnp.argmin tie-break.
// ---------------------------------------------------------------------------
__global__ __launch_bounds__(256) void knn_partial(
    const float* __restrict__ pred_pts, const float* __restrict__ targ_pts,
    float* __restrict__ wsM, int* __restrict__ wsI, int nslices)
{
    const int slice = NPTS / nslices;
    const int c   = blockIdx.z;
    const int dir = c >> 1, b = c & 1;
    const float* xp = (dir == 0 ? targ_pts : pred_pts) + (size_t)b * NPTS * 3;
    const float* yp = (dir == 0 ? pred_pts : targ_pts) + (size_t)b * NPTS * 3;
    const int s = blockIdx.y;
    const int n = blockIdx.x * 256 + threadIdx.x;

    __shared__ float4 sy[TILE];

    float x0 = 0.f, x1 = 0.f, x2 = 0.f;
    const bool active = (n < NPTS);
    if (active) {
        x0 = xp[n * 3 + 0];
        x1 = xp[n * 3 + 1];
        x2 = xp[n * 3 + 2];
    }

    float best = -1e30f;
    int   bidx = 0;

    const int jstart = s * slice, jend = jstart + slice;
    for (int t0 = jstart; t0 < jend; t0 += TILE) {
        const int cnt = min(TILE, jend - t0);
        __syncthreads();   // protect LDS from previous pass readers
        for (int j = threadIdx.x; j < cnt; j += 256) {
            const float a  = yp[(size_t)(t0 + j) * 3 + 0];
            const float bb = yp[(size_t)(t0 + j) * 3 + 1];
            const float cc = yp[(size_t)(t0 + j) * 3 + 2];
            const float hy = -0.5f * (a * a + bb * bb + cc * cc);
            sy[j] = make_float4(a, bb, cc, hy);
        }
        __syncthreads();
#pragma unroll 4
        for (int j = 0; j < cnt; ++j) {
            const float4 y = sy[j];   // broadcast read: all lanes same addr
            const float m = fmaf(x0, y.x, fmaf(x1, y.y, fmaf(x2, y.z, y.w)));
            if (m > best) { best = m; bidx = t0 + j; }
        }
    }

    if (active) {
        const size_t o = ((size_t)(c * nslices + s)) * NPTS + n;
        wsM[o] = best;
        wsI[o] = bidx;
    }
}

// ---------------------------------------------------------------------------
// Kernel B: combine slice partials, compute Welsch term + normal-cosine term,
// block-reduce to one float2 partial per block (deterministic, no atomics).
// ---------------------------------------------------------------------------
__global__ __launch_bounds__(256) void finalize(
    const float* __restrict__ pred_pts, const float* __restrict__ pred_nrm,
    const float* __restrict__ targ_pts, const float* __restrict__ targ_nrm,
    const float* __restrict__ wsM, const int* __restrict__ wsI,
    float2* __restrict__ wsB, int nslices)
{
    const int c   = blockIdx.y;
    const int dir = c >> 1, b = c & 1;
    const float* xp = (dir == 0 ? targ_pts : pred_pts) + (size_t)b * NPTS * 3;
    const float* xn = (dir == 0 ? targ_nrm : pred_nrm) + (size_t)b * NPTS * 3;
    const float* yn = (dir == 0 ? pred_nrm : targ_nrm) + (size_t)b * NPTS * 3;
    const int n = blockIdx.x * 256 + threadIdx.x;

    float t0 = 0.f, t1 = 0.f;
    if (n < NPTS) {
        float best = -1e30f;
        int   bidx = 0;
        for (int s = 0; s < nslices; ++s) {
            const size_t o = ((size_t)(c * nslices + s)) * NPTS + n;
            const float m = wsM[o];
            if (m > best) { best = m; bidx = wsI[o]; }   // earlier slice wins ties
        }
        const float a  = xp[n * 3 + 0];
        const float bb = xp[n * 3 + 1];
        const float cc = xp[n * 3 + 2];
        const float hx = -0.5f * (a * a + bb * bb + cc * cc);
        float d2 = -2.0f * (best + hx);
        d2 = fmaxf(d2, 0.0f);
        const float w = __expf(-(d2 * d2) * (1.0f / 0.18f));  // 2*ALPHA^2 = 0.18
        t0 = w * d2;

        const float nx0 = xn[n * 3 + 0], nx1 = xn[n * 3 + 1], nx2 = xn[n * 3 + 2];
        const float ny0 = yn[(size_t)bidx * 3 + 0];
        const float ny1 = yn[(size_t)bidx * 3 + 1];
        const float ny2 = yn[(size_t)bidx * 3 + 2];
        const float nnx = fmaxf(sqrtf(nx0 * nx0 + nx1 * nx1 + nx2 * nx2), 1e-6f);
        const float nny = fmaxf(sqrtf(ny0 * ny0 + ny1 * ny1 + ny2 * ny2), 1e-6f);
        const float cosv = (nx0 * ny0 + nx1 * ny1 + nx2 * ny2) / (nnx * nny);
        t1 = 1.0f - fabsf(cosv);
    }

    __shared__ float r0[256], r1[256];
    r0[threadIdx.x] = t0;
    r1[threadIdx.x] = t1;
    __syncthreads();
    for (int st = 128; st > 0; st >>= 1) {
        if (threadIdx.x < st) {
            r0[threadIdx.x] += r0[threadIdx.x + st];
            r1[threadIdx.x] += r1[threadIdx.x + st];
        }
        __syncthreads();
    }
    if (threadIdx.x == 0)
        wsB[blockIdx.y * gridDim.x + blockIdx.x] = make_float2(r0[0], r1[0]);
}

// ---------------------------------------------------------------------------
// Kernel C: final deterministic reduction of the 160 block partials.
// out[0] = 0.5 * sum(w*d)            (mean over B=2 of per-batch sums, both dirs)
// out[1] = sum(1-|cos|) / 20000      (mean over B*N, both dirs)
// ---------------------------------------------------------------------------
__global__ __launch_bounds__(256) void reduce_final(
    const float2* __restrict__ wsB, int nblocks, float* __restrict__ out)
{
    __shared__ float r0[256], r1[256];
    const int t = threadIdx.x;
    float s0 = 0.f, s1 = 0.f;
    for (int i = t; i < nblocks; i += 256) {
        const float2 v = wsB[i];
        s0 += v.x;
        s1 += v.y;
    }
    r0[t] = s0; r1[t] = s1;
    __syncthreads();
    for (int st = 128; st > 0; st >>= 1) {
        if (t < st) { r0[t] += r0[t + st]; r1[t] += r1[t + st]; }
        __syncthreads();
    }
    if (t == 0) {
        out[0] = 0.5f * r0[0];
        out[1] = r1[0] * (1.0f / 20000.0f);
    }
}

extern "C" void kernel_launch(void* const* d_in, const int* in_sizes, int n_in,
                              void* d_out, int out_size, void* d_ws, size_t ws_size,
                              hipStream_t stream)
{
    const float* pred_pts = (const float*)d_in[0];
    const float* pred_nrm = (const float*)d_in[1];
    const float* targ_pts = (const float*)d_in[2];
    const float* targ_nrm = (const float*)d_in[3];
    float* out = (float*)d_out;

    // Pick the largest slice count whose workspace footprint fits.
    int ns = 10;
    for (;;) {
        const size_t need = (size_t)4 * ns * NPTS * (sizeof(float) + sizeof(int))
                          + (size_t)4 * XCHUNKS * sizeof(float2);
        if (need <= ws_size || ns == 1) break;
        ns = (ns == 10) ? 5 : (ns == 5) ? 2 : 1;
    }

    float*  wsM = (float*)d_ws;                         // 4*ns*NPTS floats
    int*    wsI = (int*)(wsM + (size_t)4 * ns * NPTS);  // 4*ns*NPTS ints
    float2* wsB = (float2*)(wsI + (size_t)4 * ns * NPTS);

    dim3 gA(XCHUNKS, ns, 4);
    knn_partial<<<gA, 256, 0, stream>>>(pred_pts, targ_pts, wsM, wsI, ns);

    dim3 gB(XCHUNKS, 4);
    finalize<<<gB, 256, 0, stream>>>(pred_pts, pred_nrm, targ_pts, targ_nrm,
                                     wsM, wsI, wsB, ns);

    reduce_final<<<1, 256, 0, stream>>>(wsB, XCHUNKS * 4, out);
}

// Round 2
// 72.105 us; speedup vs baseline: 1.1196x; 1.1196x over previous
//
#include <hip/hip_runtime.h>
#include <math.h>

#define NPTS 10000
#define XPT 4              // x-points per thread in pass A
#define AXCH 10            // ceil(10000 / (256*XPT))
#define TILE 500           // y-points staged per LDS pass (float4 = 8 KB)
#define BXCH 40            // ceil(10000/256) for pass B

// ---------------------------------------------------------------------------
// Pass A: per (combo, slice, x-chunk) partial max of m_j = dot(x,y_j)-0.5|y_j|^2
// (equivalent to min d2). NO index tracking -> inner pair = 3 FMA + 1/2 max3.
// Each thread carries XPT x-points; j unrolled by 2 so fmax pairs fuse to max3.
// ---------------------------------------------------------------------------
__global__ __launch_bounds__(256) void knn_max(
    const float* __restrict__ pred_pts, const float* __restrict__ targ_pts,
    float* __restrict__ wsM, int nslices)
{
    const int slice = NPTS / nslices;
    const int c   = blockIdx.z;
    const int dir = c >> 1, b = c & 1;
    const float* xp = (dir == 0 ? targ_pts : pred_pts) + (size_t)b * NPTS * 3;
    const float* yp = (dir == 0 ? pred_pts : targ_pts) + (size_t)b * NPTS * 3;
    const int s = blockIdx.y;
    const int base = blockIdx.x * (256 * XPT) + threadIdx.x;

    __shared__ float4 sy[TILE];

    float xx[XPT][3];
    int   xi[XPT];
#pragma unroll
    for (int k = 0; k < XPT; ++k) {
        const int n = base + k * 256;
        xi[k] = n;
        const int nn = (n < NPTS) ? n : (NPTS - 1);   // clamp; discard on store
        xx[k][0] = xp[nn * 3 + 0];
        xx[k][1] = xp[nn * 3 + 1];
        xx[k][2] = xp[nn * 3 + 2];
    }
    float best[XPT];
#pragma unroll
    for (int k = 0; k < XPT; ++k) best[k] = -1e30f;

    const int jstart = s * slice, jend = jstart + slice;
    for (int t0 = jstart; t0 < jend; t0 += TILE) {
        const int cnt = min(TILE, jend - t0);        // always even here
        __syncthreads();
        for (int j = threadIdx.x; j < cnt; j += 256) {
            const float a  = yp[(t0 + j) * 3 + 0];
            const float bb = yp[(t0 + j) * 3 + 1];
            const float cc = yp[(t0 + j) * 3 + 2];
            sy[j] = make_float4(a, bb, cc, -0.5f * (a * a + bb * bb + cc * cc));
        }
        __syncthreads();
#pragma unroll 4
        for (int j = 0; j < cnt; j += 2) {
            const float4 ya = sy[j];       // broadcast reads: conflict-free
            const float4 yb = sy[j + 1];
#pragma unroll
            for (int k = 0; k < XPT; ++k) {
                const float ma = fmaf(xx[k][0], ya.x,
                                 fmaf(xx[k][1], ya.y,
                                 fmaf(xx[k][2], ya.z, ya.w)));
                const float mb = fmaf(xx[k][0], yb.x,
                                 fmaf(xx[k][1], yb.y,
                                 fmaf(xx[k][2], yb.z, yb.w)));
                best[k] = fmaxf(fmaxf(best[k], ma), mb);   // -> v_max3_f32
            }
        }
    }
#pragma unroll
    for (int k = 0; k < XPT; ++k)
        if (xi[k] < NPTS)
            wsM[((size_t)(c * nslices + s)) * NPTS + xi[k]] = best[k];
}

// ---------------------------------------------------------------------------
// Pass B: per x -- pick winning slice (strict >, ascending => earliest slice
// wins ties), rescan ONLY that slice for the first-occurrence argmax, then
// Welsch term + normal-cosine term, block-reduce to float2 per block.
// ---------------------------------------------------------------------------
__global__ __launch_bounds__(256) void finalize(
    const float* __restrict__ pred_pts, const float* __restrict__ pred_nrm,
    const float* __restrict__ targ_pts, const float* __restrict__ targ_nrm,
    const float* __restrict__ wsM, float2* __restrict__ wsB, int nslices)
{
    const int c   = blockIdx.y;
    const int dir = c >> 1, b = c & 1;
    const float* xp = (dir == 0 ? targ_pts : pred_pts) + (size_t)b * NPTS * 3;
    const float* xn = (dir == 0 ? targ_nrm : pred_nrm) + (size_t)b * NPTS * 3;
    const float* yp = (dir == 0 ? pred_pts : targ_pts) + (size_t)b * NPTS * 3;
    const float* yn = (dir == 0 ? pred_nrm : targ_nrm) + (size_t)b * NPTS * 3;
    const int n = blockIdx.x * 256 + threadIdx.x;

    float t0 = 0.f, t1 = 0.f;
    if (n < NPTS) {
        // 1) winning slice from pass-A partial maxima
        float bm = -1e30f;
        int   bs = 0;
        for (int s = 0; s < nslices; ++s) {
            const float m = wsM[((size_t)(c * nslices + s)) * NPTS + n];
            if (m > bm) { bm = m; bs = s; }
        }
        // 2) rescan winning slice for first-occurrence argmax
        const float a  = xp[n * 3 + 0];
        const float bb = xp[n * 3 + 1];
        const float cc = xp[n * 3 + 2];
        const int slice = NPTS / nslices;
        const int j0 = bs * slice;
        float rb = -1e30f;
        int bidx = 0;
#pragma unroll 4
        for (int j = 0; j < slice; ++j) {
            const int jj = j0 + j;
            const float ya = yp[jj * 3 + 0];
            const float yb = yp[jj * 3 + 1];
            const float yc = yp[jj * 3 + 2];
            const float hy = -0.5f * (ya * ya + yb * yb + yc * yc);
            const float m  = fmaf(a, ya, fmaf(bb, yb, fmaf(cc, yc, hy)));
            if (m > rb) { rb = m; bidx = jj; }
        }
        // 3) Welsch robust term
        const float hx = -0.5f * (a * a + bb * bb + cc * cc);
        float d2 = -2.0f * (rb + hx);
        d2 = fmaxf(d2, 0.0f);
        const float w = __expf(-(d2 * d2) * (1.0f / 0.18f));  // 2*ALPHA^2
        t0 = w * d2;
        // 4) normal cosine term
        const float nx0 = xn[n * 3 + 0], nx1 = xn[n * 3 + 1], nx2 = xn[n * 3 + 2];
        const float ny0 = yn[(size_t)bidx * 3 + 0];
        const float ny1 = yn[(size_t)bidx * 3 + 1];
        const float ny2 = yn[(size_t)bidx * 3 + 2];
        const float nnx = fmaxf(sqrtf(nx0 * nx0 + nx1 * nx1 + nx2 * nx2), 1e-6f);
        const float nny = fmaxf(sqrtf(ny0 * ny0 + ny1 * ny1 + ny2 * ny2), 1e-6f);
        const float cosv = (nx0 * ny0 + nx1 * ny1 + nx2 * ny2) / (nnx * nny);
        t1 = 1.0f - fabsf(cosv);
    }

    __shared__ float r0[256], r1[256];
    r0[threadIdx.x] = t0;
    r1[threadIdx.x] = t1;
    __syncthreads();
    for (int st = 128; st > 0; st >>= 1) {
        if (threadIdx.x < st) {
            r0[threadIdx.x] += r0[threadIdx.x + st];
            r1[threadIdx.x] += r1[threadIdx.x + st];
        }
        __syncthreads();
    }
    if (threadIdx.x == 0)
        wsB[blockIdx.y * gridDim.x + blockIdx.x] = make_float2(r0[0], r1[0]);
}

// ---------------------------------------------------------------------------
// Final deterministic reduction of the 160 block partials.
// ---------------------------------------------------------------------------
__global__ __launch_bounds__(256) void reduce_final(
    const float2* __restrict__ wsB, int nblocks, float* __restrict__ out)
{
    __shared__ float r0[256], r1[256];
    const int t = threadIdx.x;
    float s0 = 0.f, s1 = 0.f;
    for (int i = t; i < nblocks; i += 256) {
        const float2 v = wsB[i];
        s0 += v.x;
        s1 += v.y;
    }
    r0[t] = s0; r1[t] = s1;
    __syncthreads();
    for (int st = 128; st > 0; st >>= 1) {
        if (t < st) { r0[t] += r0[t + st]; r1[t] += r1[t + st]; }
        __syncthreads();
    }
    if (t == 0) {
        out[0] = 0.5f * r0[0];                 // mean over B=2 of per-batch sums
        out[1] = r1[0] * (1.0f / 20000.0f);    // mean over B*N, both dirs
    }
}

extern "C" void kernel_launch(void* const* d_in, const int* in_sizes, int n_in,
                              void* d_out, int out_size, void* d_ws, size_t ws_size,
                              hipStream_t stream)
{
    const float* pred_pts = (const float*)d_in[0];
    const float* pred_nrm = (const float*)d_in[1];
    const float* targ_pts = (const float*)d_in[2];
    const float* targ_nrm = (const float*)d_in[3];
    float* out = (float*)d_out;

    // Largest slice count whose float-only workspace fits (all divide NPTS,
    // all give even slice sizes).
    const int ladder[5] = {40, 20, 10, 5, 2};
    int ns = 2;
    for (int i = 0; i < 5; ++i) {
        const size_t need = (size_t)4 * ladder[i] * NPTS * sizeof(float)
                          + (size_t)4 * BXCH * sizeof(float2) + 256;
        if (need <= ws_size) { ns = ladder[i]; break; }
    }

    float*  wsM = (float*)d_ws;                         // 4*ns*NPTS floats
    float2* wsB = (float2*)(wsM + (size_t)4 * ns * NPTS);

    dim3 gA(AXCH, ns, 4);
    knn_max<<<gA, 256, 0, stream>>>(pred_pts, targ_pts, wsM, ns);

    dim3 gB(BXCH, 4);
    finalize<<<gB, 256, 0, stream>>>(pred_pts, pred_nrm, targ_pts, targ_nrm,
                                     wsM, wsB, ns);

    reduce_final<<<1, 256, 0, stream>>>(wsB, BXCH * 4, out);
}

// Round 3
// 56.807 us; speedup vs baseline: 1.4211x; 1.2693x over previous
//
#include <hip/hip_runtime.h>
#include <math.h>

#define NPTS 10000
#define XPT 8              // x-points per thread in pass A
#define AXCH 5             // ceil(10000 / (256*XPT))
#define TILE 500           // y-points staged per LDS pass (float4 = 8 KB)

// ---------------------------------------------------------------------------
// Pass A: per (combo, slice, x-chunk) partial max of m_j = dot(x,y_j)-0.5|y_j|^2
// (equiv. min d2). No index tracking: inner pair = 3 FMA + 1/2 max3.
// XPT=8 so each pair of LDS b128 broadcast reads feeds 16 lane-pairs.
// ---------------------------------------------------------------------------
__global__ __launch_bounds__(256) void knn_max(
    const float* __restrict__ pred_pts, const float* __restrict__ targ_pts,
    float* __restrict__ wsM, int nslices)
{
    const int slice = NPTS / nslices;
    const int c   = blockIdx.z;
    const int dir = c >> 1, b = c & 1;
    const float* xp = (dir == 0 ? targ_pts : pred_pts) + (size_t)b * NPTS * 3;
    const float* yp = (dir == 0 ? pred_pts : targ_pts) + (size_t)b * NPTS * 3;
    const int s = blockIdx.y;
    const int base = blockIdx.x * (256 * XPT) + threadIdx.x;

    __shared__ float4 sy[TILE];

    float xx[XPT][3];
#pragma unroll
    for (int k = 0; k < XPT; ++k) {
        const int n = base + k * 256;
        const int nn = (n < NPTS) ? n : (NPTS - 1);   // clamp; discard on store
        xx[k][0] = xp[nn * 3 + 0];
        xx[k][1] = xp[nn * 3 + 1];
        xx[k][2] = xp[nn * 3 + 2];
    }
    float best[XPT];
#pragma unroll
    for (int k = 0; k < XPT; ++k) best[k] = -1e30f;

    const int jstart = s * slice, jend = jstart + slice;
    for (int t0 = jstart; t0 < jend; t0 += TILE) {
        const int cnt = min(TILE, jend - t0);        // even for all ladder ns
        __syncthreads();
        for (int j = threadIdx.x; j < cnt; j += 256) {
            const float a  = yp[(t0 + j) * 3 + 0];
            const float bb = yp[(t0 + j) * 3 + 1];
            const float cc = yp[(t0 + j) * 3 + 2];
            sy[j] = make_float4(a, bb, cc, -0.5f * (a * a + bb * bb + cc * cc));
        }
        __syncthreads();
#pragma unroll 4
        for (int j = 0; j < cnt; j += 2) {
            const float4 ya = sy[j];       // broadcast reads: conflict-free
            const float4 yb = sy[j + 1];
#pragma unroll
            for (int k = 0; k < XPT; ++k) {
                const float ma = fmaf(xx[k][0], ya.x,
                                 fmaf(xx[k][1], ya.y,
                                 fmaf(xx[k][2], ya.z, ya.w)));
                const float mb = fmaf(xx[k][0], yb.x,
                                 fmaf(xx[k][1], yb.y,
                                 fmaf(xx[k][2], yb.z, yb.w)));
                best[k] = fmaxf(fmaxf(best[k], ma), mb);   // -> v_max3_f32
            }
        }
    }
#pragma unroll
    for (int k = 0; k < XPT; ++k) {
        const int n = base + k * 256;
        if (n < NPTS)
            wsM[((size_t)(c * nslices + s)) * NPTS + n] = best[k];
    }
}

// ---------------------------------------------------------------------------
// Pass B: 8-lane group per x-point.
//   1) lane-parallel slice select (max m, tie -> smaller s) via shfl butterfly
//   2) lane-parallel rescan of the winning slice (stride-8 -> coalesced),
//      (max m, tie -> smaller j) -> exact first-occurrence argmax
//   3) lane 0: Welsch term + normal-cosine term; block-reduce to float2.
// ---------------------------------------------------------------------------
__global__ __launch_bounds__(256) void finalize(
    const float* __restrict__ pred_pts, const float* __restrict__ pred_nrm,
    const float* __restrict__ targ_pts, const float* __restrict__ targ_nrm,
    const float* __restrict__ wsM, float2* __restrict__ wsB, int nslices)
{
    const int c   = blockIdx.y;
    const int dir = c >> 1, b = c & 1;
    const float* xp = (dir == 0 ? targ_pts : pred_pts) + (size_t)b * NPTS * 3;
    const float* xn = (dir == 0 ? targ_nrm : pred_nrm) + (size_t)b * NPTS * 3;
    const float* yp = (dir == 0 ? pred_pts : targ_pts) + (size_t)b * NPTS * 3;
    const float* yn = (dir == 0 ? pred_nrm : targ_nrm) + (size_t)b * NPTS * 3;

    const int lane = threadIdx.x & 7;
    const int n = blockIdx.x * 32 + (threadIdx.x >> 3);

    float t0 = 0.f, t1 = 0.f;
    if (n < NPTS) {
        // 1) slice select, lane-parallel over s
        float bm = -1e30f;
        int   bs = 1 << 30;
        for (int s = lane; s < nslices; s += 8) {
            const float m = wsM[((size_t)(c * nslices + s)) * NPTS + n];
            if (m > bm) { bm = m; bs = s; }
        }
#pragma unroll
        for (int w = 1; w < 8; w <<= 1) {
            const float mo = __shfl_xor(bm, w);
            const int   so = __shfl_xor(bs, w);
            if (mo > bm || (mo == bm && so < bs)) { bm = mo; bs = so; }
        }
        // 2) rescan winning slice, lane-parallel over j
        const float a  = xp[n * 3 + 0];
        const float bb = xp[n * 3 + 1];
        const float cc = xp[n * 3 + 2];
        const int slice = NPTS / nslices;
        const int j0 = bs * slice;
        float rb = -1e30f;
        int bidx = 1 << 30;
        for (int j = j0 + lane; j < j0 + slice; j += 8) {
            const float ya = yp[j * 3 + 0];
            const float yb = yp[j * 3 + 1];
            const float yc = yp[j * 3 + 2];
            const float hy = -0.5f * (ya * ya + yb * yb + yc * yc);
            const float m  = fmaf(a, ya, fmaf(bb, yb, fmaf(cc, yc, hy)));
            if (m > rb) { rb = m; bidx = j; }
        }
#pragma unroll
        for (int w = 1; w < 8; w <<= 1) {
            const float mo = __shfl_xor(rb, w);
            const int   jo = __shfl_xor(bidx, w);
            if (mo > rb || (mo == rb && jo < bidx)) { rb = mo; bidx = jo; }
        }
        // 3) terms on lane 0 only
        if (lane == 0) {
            const float hx = -0.5f * (a * a + bb * bb + cc * cc);
            float d2 = -2.0f * (rb + hx);
            d2 = fmaxf(d2, 0.0f);
            const float w = __expf(-(d2 * d2) * (1.0f / 0.18f));  // 2*ALPHA^2
            t0 = w * d2;
            const float nx0 = xn[n * 3 + 0], nx1 = xn[n * 3 + 1], nx2 = xn[n * 3 + 2];
            const float ny0 = yn[(size_t)bidx * 3 + 0];
            const float ny1 = yn[(size_t)bidx * 3 + 1];
            const float ny2 = yn[(size_t)bidx * 3 + 2];
            const float nnx = fmaxf(sqrtf(nx0 * nx0 + nx1 * nx1 + nx2 * nx2), 1e-6f);
            const float nny = fmaxf(sqrtf(ny0 * ny0 + ny1 * ny1 + ny2 * ny2), 1e-6f);
            const float cosv = (nx0 * ny0 + nx1 * ny1 + nx2 * ny2) / (nnx * nny);
            t1 = 1.0f - fabsf(cosv);
        }
    }

    __shared__ float r0[256], r1[256];
    r0[threadIdx.x] = t0;
    r1[threadIdx.x] = t1;
    __syncthreads();
    for (int st = 128; st > 0; st >>= 1) {
        if (threadIdx.x < st) {
            r0[threadIdx.x] += r0[threadIdx.x + st];
            r1[threadIdx.x] += r1[threadIdx.x + st];
        }
        __syncthreads();
    }
    if (threadIdx.x == 0)
        wsB[blockIdx.y * gridDim.x + blockIdx.x] = make_float2(r0[0], r1[0]);
}

// ---------------------------------------------------------------------------
// Final deterministic reduction of the block partials.
// ---------------------------------------------------------------------------
__global__ __launch_bounds__(256) void reduce_final(
    const float2* __restrict__ wsB, int nblocks, float* __restrict__ out)
{
    __shared__ float r0[256], r1[256];
    const int t = threadIdx.x;
    float s0 = 0.f, s1 = 0.f;
    for (int i = t; i < nblocks; i += 256) {
        const float2 v = wsB[i];
        s0 += v.x;
        s1 += v.y;
    }
    r0[t] = s0; r1[t] = s1;
    __syncthreads();
    for (int st = 128; st > 0; st >>= 1) {
        if (t < st) { r0[t] += r0[t + st]; r1[t] += r1[t + st]; }
        __syncthreads();
    }
    if (t == 0) {
        out[0] = 0.5f * r0[0];                 // mean over B=2 of per-batch sums
        out[1] = r1[0] * (1.0f / 20000.0f);    // mean over B*N, both dirs
    }
}

extern "C" void kernel_launch(void* const* d_in, const int* in_sizes, int n_in,
                              void* d_out, int out_size, void* d_ws, size_t ws_size,
                              hipStream_t stream)
{
    const float* pred_pts = (const float*)d_in[0];
    const float* pred_nrm = (const float*)d_in[1];
    const float* targ_pts = (const float*)d_in[2];
    const float* targ_nrm = (const float*)d_in[3];
    float* out = (float*)d_out;

    const int BXCH = (NPTS + 31) / 32;   // 313 blocks per combo in pass B

    // Largest slice count whose float-only workspace fits.
    const int ladder[5] = {40, 20, 10, 5, 2};
    int ns = 2;
    for (int i = 0; i < 5; ++i) {
        const size_t need = (size_t)4 * ladder[i] * NPTS * sizeof(float)
                          + (size_t)4 * BXCH * sizeof(float2) + 256;
        if (need <= ws_size) { ns = ladder[i]; break; }
    }

    float*  wsM = (float*)d_ws;                         // 4*ns*NPTS floats
    float2* wsB = (float2*)(wsM + (size_t)4 * ns * NPTS);

    dim3 gA(AXCH, ns, 4);
    knn_max<<<gA, 256, 0, stream>>>(pred_pts, targ_pts, wsM, ns);

    dim3 gB(BXCH, 4);
    finalize<<<gB, 256, 0, stream>>>(pred_pts, pred_nrm, targ_pts, targ_nrm,
                                     wsM, wsB, ns);

    reduce_final<<<1, 256, 0, stream>>>(wsB, BXCH * 4, out);
}

// Round 4
// 54.892 us; speedup vs baseline: 1.4706x; 1.0349x over previous
//
#include <hip/hip_runtime.h>
#include <math.h>

#define NPTS 10000
#define XPT 8              // x-points per thread: 4 packed-FP32 + 4 scalar
#define AXCH 5             // ceil(10000 / (256*XPT))
#define TILE 500           // y-points staged per LDS pass (pair-packed, 8 KB)

typedef float float2v __attribute__((ext_vector_type(2)));

// d = a*b + c (packed 2xf32, FP64 pipe). Default VOP3P modifiers = plain packed.
#define PKFMA(d, a, b, c) \
    asm("v_pk_fma_f32 %0, %1, %2, %3" : "=v"(d) : "v"(a), "v"(b), "v"(c))

// ---------------------------------------------------------------------------
// Pass A: per (combo, slice, x-chunk) partial max of m_j = dot(x,y_j)-0.5|y_j|^2.
// LDS pair-packed: spk[2p]={x0,x1,y0,y1}, spk[2p+1]={z0,z1,h0,h1} for j-pair p
// -> 2 broadcast ds_read_b128 feed 16 lane-pairs. 4 x's go through v_pk_fma_f32
// (DP pipe), 4 through scalar fmaf (SP pipe): both vector pipes run in parallel.
// ---------------------------------------------------------------------------
__global__ __launch_bounds__(256, 4) void knn_max(
    const float* __restrict__ pred_pts, const float* __restrict__ targ_pts,
    float* __restrict__ wsM, int nslices)
{
    const int slice = NPTS / nslices;          // ladder keeps this even
    const int c   = blockIdx.z;
    const int dir = c >> 1, b = c & 1;
    const float* xp = (dir == 0 ? targ_pts : pred_pts) + (size_t)b * NPTS * 3;
    const float* yp = (dir == 0 ? pred_pts : targ_pts) + (size_t)b * NPTS * 3;
    const int s = blockIdx.y;
    const int base = blockIdx.x * (256 * XPT) + threadIdx.x;

    __shared__ float4 spk[TILE];               // 2 float4 per j-pair

    float2v xb[4][3];                          // packed-k x broadcasts
    float   xs[4][3];                          // scalar-k x comps
#pragma unroll
    for (int k = 0; k < 8; ++k) {
        const int n = base + k * 256;
        const int nn = (n < NPTS) ? n : (NPTS - 1);   // clamp; discard on store
        const float v0 = xp[nn * 3 + 0];
        const float v1 = xp[nn * 3 + 1];
        const float v2 = xp[nn * 3 + 2];
        if (k < 4) {
            xb[k][0] = (float2v){v0, v0};
            xb[k][1] = (float2v){v1, v1};
            xb[k][2] = (float2v){v2, v2};
        } else {
            xs[k - 4][0] = v0; xs[k - 4][1] = v1; xs[k - 4][2] = v2;
        }
    }
    float best[8];
#pragma unroll
    for (int k = 0; k < 8; ++k) best[k] = -1e30f;

    const int jstart = s * slice, jend = jstart + slice;
    for (int t0 = jstart; t0 < jend; t0 += TILE) {
        const int cnt = min(TILE, jend - t0);  // even for all ladder ns
        const int np  = cnt >> 1;
        __syncthreads();
        for (int p = threadIdx.x; p < np; p += 256) {
            const int j = t0 + 2 * p;
            const float a0 = yp[j * 3 + 0], b0 = yp[j * 3 + 1], c0 = yp[j * 3 + 2];
            const float a1 = yp[j * 3 + 3], b1 = yp[j * 3 + 4], c1 = yp[j * 3 + 5];
            spk[2 * p]     = make_float4(a0, a1, b0, b1);
            spk[2 * p + 1] = make_float4(c0, c1,
                                         -0.5f * (a0 * a0 + b0 * b0 + c0 * c0),
                                         -0.5f * (a1 * a1 + b1 * b1 + c1 * c1));
        }
        __syncthreads();
#pragma unroll 2
        for (int p = 0; p < np; ++p) {
            const float4 A = spk[2 * p];       // {x0,x1,y0,y1} broadcast
            const float4 B = spk[2 * p + 1];   // {z0,z1,h0,h1}
            const float2v px = {A.x, A.y}, py = {A.z, A.w};
            const float2v pz = {B.x, B.y}, pw = {B.z, B.w};
#pragma unroll
            for (int k = 0; k < 4; ++k) {      // DP pipe: 3 pk_fma = 2 dots
                float2v t;
                PKFMA(t, xb[k][2], pz, pw);
                PKFMA(t, xb[k][1], py, t);
                PKFMA(t, xb[k][0], px, t);
                best[k] = fmaxf(fmaxf(best[k], t.x), t.y);   // v_max3
            }
#pragma unroll
            for (int k = 0; k < 4; ++k) {      // SP pipe: scalar fmaf chains
                const float ma = fmaf(xs[k][0], A.x,
                                 fmaf(xs[k][1], A.z, fmaf(xs[k][2], B.x, B.z)));
                const float mb = fmaf(xs[k][0], A.y,
                                 fmaf(xs[k][1], A.w, fmaf(xs[k][2], B.y, B.w)));
                best[4 + k] = fmaxf(fmaxf(best[4 + k], ma), mb);
            }
        }
    }
#pragma unroll
    for (int k = 0; k < 8; ++k) {
        const int n = base + k * 256;
        if (n < NPTS)
            wsM[((size_t)(c * nslices + s)) * NPTS + n] = best[k];
    }
}

// ---------------------------------------------------------------------------
// Pass B: 8-lane group per x-point. Slice-select via pass-A maxima (tie ->
// smaller s), lane-parallel rescan of the winning slice (tie -> smaller j,
// exact first-occurrence argmax; scalar fmaf chain == packed lo-half chain
// bit-exactly), then Welsch + normal-cosine terms; block-reduce.
// ---------------------------------------------------------------------------
__global__ __launch_bounds__(256) void finalize(
    const float* __restrict__ pred_pts, const float* __restrict__ pred_nrm,
    const float* __restrict__ targ_pts, const float* __restrict__ targ_nrm,
    const float* __restrict__ wsM, float2* __restrict__ wsB, int nslices)
{
    const int c   = blockIdx.y;
    const int dir = c >> 1, b = c & 1;
    const float* xp = (dir == 0 ? targ_pts : pred_pts) + (size_t)b * NPTS * 3;
    const float* xn = (dir == 0 ? targ_nrm : pred_nrm) + (size_t)b * NPTS * 3;
    const float* yp = (dir == 0 ? pred_pts : targ_pts) + (size_t)b * NPTS * 3;
    const float* yn = (dir == 0 ? pred_nrm : targ_nrm) + (size_t)b * NPTS * 3;

    const int lane = threadIdx.x & 7;
    const int n = blockIdx.x * 32 + (threadIdx.x >> 3);

    float t0 = 0.f, t1 = 0.f;
    if (n < NPTS) {
        float bm = -1e30f;
        int   bs = 1 << 30;
        for (int s = lane; s < nslices; s += 8) {
            const float m = wsM[((size_t)(c * nslices + s)) * NPTS + n];
            if (m > bm) { bm = m; bs = s; }
        }
#pragma unroll
        for (int w = 1; w < 8; w <<= 1) {
            const float mo = __shfl_xor(bm, w);
            const int   so = __shfl_xor(bs, w);
            if (mo > bm || (mo == bm && so < bs)) { bm = mo; bs = so; }
        }
        const float a  = xp[n * 3 + 0];
        const float bb = xp[n * 3 + 1];
        const float cc = xp[n * 3 + 2];
        const int slice = NPTS / nslices;
        const int j0 = bs * slice;
        float rb = -1e30f;
        int bidx = 1 << 30;
        for (int j = j0 + lane; j < j0 + slice; j += 8) {
            const float ya = yp[j * 3 + 0];
            const float yb = yp[j * 3 + 1];
            const float yc = yp[j * 3 + 2];
            const float hy = -0.5f * (ya * ya + yb * yb + yc * yc);
            const float m  = fmaf(a, ya, fmaf(bb, yb, fmaf(cc, yc, hy)));
            if (m > rb) { rb = m; bidx = j; }
        }
#pragma unroll
        for (int w = 1; w < 8; w <<= 1) {
            const float mo = __shfl_xor(rb, w);
            const int   jo = __shfl_xor(bidx, w);
            if (mo > rb || (mo == rb && jo < bidx)) { rb = mo; bidx = jo; }
        }
        if (lane == 0) {
            const float hx = -0.5f * (a * a + bb * bb + cc * cc);
            float d2 = -2.0f * (rb + hx);
            d2 = fmaxf(d2, 0.0f);
            const float w = __expf(-(d2 * d2) * (1.0f / 0.18f));  // 2*ALPHA^2
            t0 = w * d2;
            const float nx0 = xn[n * 3 + 0], nx1 = xn[n * 3 + 1], nx2 = xn[n * 3 + 2];
            const float ny0 = yn[(size_t)bidx * 3 + 0];
            const float ny1 = yn[(size_t)bidx * 3 + 1];
            const float ny2 = yn[(size_t)bidx * 3 + 2];
            const float nnx = fmaxf(sqrtf(nx0 * nx0 + nx1 * nx1 + nx2 * nx2), 1e-6f);
            const float nny = fmaxf(sqrtf(ny0 * ny0 + ny1 * ny1 + ny2 * ny2), 1e-6f);
            const float cosv = (nx0 * ny0 + nx1 * ny1 + nx2 * ny2) / (nnx * nny);
            t1 = 1.0f - fabsf(cosv);
        }
    }

    __shared__ float r0[256], r1[256];
    r0[threadIdx.x] = t0;
    r1[threadIdx.x] = t1;
    __syncthreads();
    for (int st = 128; st > 0; st >>= 1) {
        if (threadIdx.x < st) {
            r0[threadIdx.x] += r0[threadIdx.x + st];
            r1[threadIdx.x] += r1[threadIdx.x + st];
        }
        __syncthreads();
    }
    if (threadIdx.x == 0)
        wsB[blockIdx.y * gridDim.x + blockIdx.x] = make_float2(r0[0], r1[0]);
}

// ---------------------------------------------------------------------------
// Final deterministic reduction of the block partials.
// ---------------------------------------------------------------------------
__global__ __launch_bounds__(256) void reduce_final(
    const float2* __restrict__ wsB, int nblocks, float* __restrict__ out)
{
    __shared__ float r0[256], r1[256];
    const int t = threadIdx.x;
    float s0 = 0.f, s1 = 0.f;
    for (int i = t; i < nblocks; i += 256) {
        const float2 v = wsB[i];
        s0 += v.x;
        s1 += v.y;
    }
    r0[t] = s0; r1[t] = s1;
    __syncthreads();
    for (int st = 128; st > 0; st >>= 1) {
        if (t < st) { r0[t] += r0[t + st]; r1[t] += r1[t + st]; }
        __syncthreads();
    }
    if (t == 0) {
        out[0] = 0.5f * r0[0];                 // mean over B=2 of per-batch sums
        out[1] = r1[0] * (1.0f / 20000.0f);    // mean over B*N, both dirs
    }
}

extern "C" void kernel_launch(void* const* d_in, const int* in_sizes, int n_in,
                              void* d_out, int out_size, void* d_ws, size_t ws_size,
                              hipStream_t stream)
{
    const float* pred_pts = (const float*)d_in[0];
    const float* pred_nrm = (const float*)d_in[1];
    const float* targ_pts = (const float*)d_in[2];
    const float* targ_nrm = (const float*)d_in[3];
    float* out = (float*)d_out;

    const int BXCH = (NPTS + 31) / 32;   // 313 blocks per combo in pass B

    // Largest slice count whose workspace fits; all give EVEN slice sizes.
    const int ladder[4] = {50, 40, 25, 10};
    int ns = 10;
    for (int i = 0; i < 4; ++i) {
        const size_t need = (size_t)4 * ladder[i] * NPTS * sizeof(float)
                          + (size_t)4 * BXCH * sizeof(float2) + 256;
        if (need <= ws_size) { ns = ladder[i]; break; }
    }

    float*  wsM = (float*)d_ws;                         // 4*ns*NPTS floats
    float2* wsB = (float2*)(wsM + (size_t)4 * ns * NPTS);

    dim3 gA(AXCH, ns, 4);
    knn_max<<<gA, 256, 0, stream>>>(pred_pts, targ_pts, wsM, ns);

    dim3 gB(BXCH, 4);
    finalize<<<gB, 256, 0, stream>>>(pred_pts, pred_nrm, targ_pts, targ_nrm,
                                     wsM, wsB, ns);

    reduce_final<<<1, 256, 0, stream>>>(wsB, BXCH * 4, out);
}